// Round 10
// baseline (34.062 us; speedup 1.0000x reference)
//
#include <hip/hip_runtime.h>
#include <math.h>

// Problem constants
constexpr int NT = 32;      // components
constexpr int ND = 1024;    // dim
constexpr int NB = 4096;    // batch
constexpr int NSLICE = 16;  // d-slices (64 d each)
constexpr int NRG    = 64;  // row-groups (64 rows each)
constexpr int QROWS  = NB + 1;   // 4096 quad rows + 1 phantom c2 row
constexpr int NBLK_MID = 256;

// Workspace layout (float offsets)
//  klg : [B][T]                                   @ 0        (131072)
//  lpi : [B][T]                                   @ 131072   (131072)
//  qp  : [16][4097][32] slice partials (+c2 row)  @ 262144   (2097664)
//  Pg  : [256][32] per-mid-block partial klg sums @ 2359808  (8192)
//  Pp  : [256][32] per-mid-block partial lpi sums @ 2368000  (8192)
constexpr int OFF_LPI = 131072;
constexpr int OFF_QP  = 262144;
constexpr int OFF_PG  = 2359808;
constexpr int OFF_PP  = 2368000;

// ---------------------------------------------------------------------------
// Kernel B v8 "self-contained slice GEMM": block (s, rg) handles d-slice s
// (64 d = 16 chunks) x 64 rows. iv/m2 recomputed in-block from mu/rho
// (1 float4/thread of softplus -- removes k_stats and the ivc/m2c global
// round-trip). LDS 32 KB -> 4 blocks/CU, 8 waves/SIMD (2x round 9's
// occupancy; the constant through r6-r9 was 2 blocks/CU + single
// generation + serialized stage->sync->compute = latency-bound).
// rg==0 blocks also store the slice's c2 partial into qp's phantom row.
// grid = 1024 blocks x 512 threads; plain coalesced stores, no atomics.
// ---------------------------------------------------------------------------
__global__ __launch_bounds__(512, 8) void k_slice(const float* __restrict__ x,
                                                  const float* __restrict__ mu,
                                                  const float* __restrict__ rho,
                                                  float* __restrict__ ws) {
  float* qp = ws + OFF_QP;

  const int bid   = blockIdx.x;
  const int slice = bid >> 6;        // 0..15
  const int rg    = bid & 63;        // 0..63
  const int tid   = threadIdx.x;

  __shared__ float xs[64 * 64];      // 16 KB [row][d-in-slice]
  __shared__ float ivs[16 * 32 * 4]; // 8 KB  slice inv_var, chunk-major
  __shared__ float m2s[16 * 32 * 4]; // 8 KB  slice -2*mu*inv_var

  // ---- Stage iv/m2: one float4 per thread (t = tid>>4, c4 = tid&15) ----
  float c2p4 = 0.0f;                 // this thread's partial of c2[t]
  {
    const int t  = tid >> 4;         // 0..31
    const int c4 = tid & 15;         // local chunk 0..15
    const float4* mug = reinterpret_cast<const float4*>(mu);
    const float4* rhg = reinterpret_cast<const float4*>(rho);
    float4 mu4 = mug[(size_t)t * 256 + slice * 16 + c4];
    float4 rh4 = rhg[(size_t)t * 256 + slice * 16 + c4];
    float mm[4] = {mu4.x, mu4.y, mu4.z, mu4.w};
    float rr[4] = {rh4.x, rh4.y, rh4.z, rh4.w};
    float iv[4], m2[4];
#pragma unroll
    for (int j = 0; j < 4; ++j) {
      float sd  = log1pf(expf(rr[j]));   // softplus
      float ivv = 1.0f / (sd * sd);
      iv[j] = ivv;
      m2[j] = -2.0f * mm[j] * ivv;
      c2p4 += mm[j] * mm[j] * ivv;
    }
    reinterpret_cast<float4*>(ivs)[c4 * 32 + t] = {iv[0], iv[1], iv[2], iv[3]};
    reinterpret_cast<float4*>(m2s)[c4 * 32 + t] = {m2[0], m2[1], m2[2], m2[3]};
  }

  // ---- Stage x: rows rg*64..+63, cols slice*64..+63 (2 float4/thread) ----
  {
    const float4* xg4 = reinterpret_cast<const float4*>(x);
    float4* xs4w = reinterpret_cast<float4*>(xs);
    const int row = tid >> 3;        // 0..63
    const int j0  = tid & 7;         // 0..7
    xs4w[row * 16 + j0]     = xg4[(size_t)(rg * 64 + row) * 256 + slice * 16 + j0];
    xs4w[row * 16 + j0 + 8] = xg4[(size_t)(rg * 64 + row) * 256 + slice * 16 + j0 + 8];
  }

  // ---- c2 partial (only rg==0 stores): reduce c2p4 over c4 (lane groups
  // of 16: t = tid>>4 so lanes t*16..t*16+15 share t) ----
  if (rg == 0) {
    float s = c2p4;
#pragma unroll
    for (int mk = 1; mk < 16; mk <<= 1) s += __shfl_xor(s, mk, 64);
    if ((tid & 15) == 0) {
      const int t = tid >> 4;
      qp[((size_t)slice * QROWS + NB) * NT + t] = s;
    }
  }
  __syncthreads();

  // ---- FMA loop: all LDS. Wave q owns rows q*8..q*8+7; lane (h,t):
  // h = lane>>5 covers chunks h*8..h*8+7, t = component. ----
  const int q    = tid >> 6;
  const int lane = tid & 63;
  const int h = lane >> 5, t = lane & 31;
  const float4* ivs4 = reinterpret_cast<const float4*>(ivs);
  const float4* m2s4 = reinterpret_cast<const float4*>(m2s);
  const float4* xsr  = reinterpret_cast<const float4*>(xs) + (size_t)(q * 8) * 16;

  float a[8] = {0.f, 0.f, 0.f, 0.f, 0.f, 0.f, 0.f, 0.f};
#pragma unroll
  for (int i = 0; i < 8; ++i) {
    const int c = h * 8 + i;         // chunk within slice (0..15)
    float4 iv4 = ivs4[c * 32 + t];
    float4 m24 = m2s4[c * 32 + t];
#pragma unroll
    for (int r = 0; r < 8; ++r) {
      float4 xv = xsr[r * 16 + c];   // broadcast ds_read_b128
      a[r] = fmaf(xv.x, fmaf(xv.x, iv4.x, m24.x), a[r]);
      a[r] = fmaf(xv.y, fmaf(xv.y, iv4.y, m24.y), a[r]);
      a[r] = fmaf(xv.z, fmaf(xv.z, iv4.z, m24.z), a[r]);
      a[r] = fmaf(xv.w, fmaf(xv.w, iv4.w, m24.w), a[r]);
    }
  }
  // combine the two 32-d sub-halves of the slice
#pragma unroll
  for (int r = 0; r < 8; ++r) a[r] += __shfl_xor(a[r], 32, 64);

  // ---- Store partial quads: plain coalesced 128 B rows ----
  if (h == 0) {
#pragma unroll
    for (int r = 0; r < 8; ++r) {
      const int row = rg * 64 + q * 8 + r;
      qp[((size_t)slice * QROWS + row) * NT + t] = a[r];
    }
  }
}

// ---------------------------------------------------------------------------
// Kernel C "mid": combine 16 slice partials (+ phantom c2 row) -> kv; beta
// scan -> log_pi; store klg/lpi; per-block partial sums -> Pg/Pp. Also
// zeroes out[0] (runs before k_final every launch -- graph replays).
// grid = 256, block = 512 (16 rows/block; thread = (row-in-block, t))
// ---------------------------------------------------------------------------
__global__ __launch_bounds__(512) void k_mid(const float* __restrict__ beta,
                                             float* __restrict__ ws,
                                             float* __restrict__ out) {
  const float* qp = ws + OFF_QP;
  float* klg = ws;
  float* lpi = ws + OFF_LPI;
  float* Pg  = ws + OFF_PG;
  float* Pp  = ws + OFF_PP;

  const int tid = threadIdx.x;
  const int rr = tid >> 5, t = tid & 31;
  const int row = blockIdx.x * 16 + rr;

  if (blockIdx.x == 0 && tid == 0) out[0] = 0.0f;

  float quad = 0.f, c2t = 0.f;
#pragma unroll
  for (int s = 0; s < NSLICE; ++s) {
    quad += qp[((size_t)s * QROWS + row) * NT + t];
    c2t  += qp[((size_t)s * QROWS + NB) * NT + t];
  }

  // kl_gaussian = log_pdfs + entropy = D/2 - 0.5*(quad + c2) (log_std_sum cancels)
  const float kv = 512.0f - 0.5f * (quad + c2t);
  klg[(size_t)row * NT + t] = kv;

  // log_pi: exclusive prefix scan of log1p(-beta) within each 32-lane group
  const float b = beta[(size_t)row * NT + t];
  const float l1m = log1pf(-b);
  float s = l1m;
#pragma unroll
  for (int d = 1; d < 32; d <<= 1) {
    float v = __shfl_up(s, (unsigned)d, 32);
    if (t >= d) s += v;
  }
  const float lp = logf(b) + (s - l1m);
  lpi[(size_t)row * NT + t] = lp;

  __shared__ float klP[16][32], lpP[16][32];
  klP[rr][t] = kv;
  lpP[rr][t] = lp;
  __syncthreads();
  if (tid < 32) {
    float sg = 0.f, sp = 0.f;
#pragma unroll
    for (int r = 0; r < 16; ++r) { sg += klP[r][tid]; sp += lpP[r][tid]; }
    Pg[(size_t)blockIdx.x * NT + tid] = sg;
    Pp[(size_t)blockIdx.x * NT + tid] = sp;
  }
}

// ---------------------------------------------------------------------------
// Kernel D: redundant per-block reduce of Pg/Pp (no contended atomics), then
// mix, softmax over T, weighted mean.
// grid = 256, block = 512 (8 waves; 16 rows/block, one per 32-lane group)
// ---------------------------------------------------------------------------
__global__ __launch_bounds__(512) void k_final(const float* __restrict__ ws,
                                               float* __restrict__ out) {
  const float* klg = ws;
  const float* lpi = ws + OFF_LPI;
  const float* Pg  = ws + OFF_PG;
  const float* Pp  = ws + OFF_PP;

  const int tid  = threadIdx.x;
  const int wave = tid >> 6, lane = tid & 63;
  const int t = tid & 31;        // component
  const int g = tid >> 5;        // reduce group 0..15 / row-in-block

  __shared__ float ngF[32], npF[32];
  __shared__ float redG[8][32], redP[8][32];
  __shared__ float red[8];

  // ---- Prologue: reduce the 256 per-mid-block partials (redundant) ----
  {
    float sg = 0.f, sp = 0.f;
#pragma unroll 4
    for (int b = g; b < NBLK_MID; b += 16) {
      sg += Pg[(size_t)b * NT + t];
      sp += Pp[(size_t)b * NT + t];
    }
    sg += __shfl_xor(sg, 32, 64);
    sp += __shfl_xor(sp, 32, 64);
    if (lane < 32) { redG[wave][t] = sg; redP[wave][t] = sp; }
  }
  __syncthreads();
  if (tid < 32) {
    float ng = 0.f, np = 0.f;
#pragma unroll
    for (int w = 0; w < 8; ++w) { ng += redG[w][tid]; np += redP[w][tid]; }
    ngF[tid] = ng;
    npF[tid] = np;
  }
  __syncthreads();

  // ---- mix + softmax over T + weighted mean ----
  const int row = blockIdx.x * 16 + g;
  const float kg = klg[(size_t)row * NT + t];
  const float lp = lpi[(size_t)row * NT + t];
  const float ng = ngF[t], np = npF[t];
  const float mix  = np / (ng + np);
  const float klgm = mix * kg;
  const float kl   = klgm + (1.0f - mix) * lp;

  float m = kl;
#pragma unroll
  for (int mk = 16; mk >= 1; mk >>= 1) m = fmaxf(m, __shfl_xor(m, mk, 64));
  const float e = expf(kl - m);
  float num = e * klgm, den = e;
#pragma unroll
  for (int mk = 16; mk >= 1; mk >>= 1) {
    num += __shfl_xor(num, mk, 64);
    den += __shfl_xor(den, mk, 64);
  }
  float s = num / den;           // per-row sum_t phi*klgm (replicated in group)
  s += __shfl_xor(s, 32, 64);    // combine the wave's two rows

  if (lane == 0) red[wave] = s;
  __syncthreads();
  if (tid == 0) {
    float tot = 0.f;
#pragma unroll
    for (int w = 0; w < 8; ++w) tot += red[w];
    atomicAdd(out, tot * (1.0f / (float)NB));
  }
}

// ---------------------------------------------------------------------------
extern "C" void kernel_launch(void* const* d_in, const int* in_sizes, int n_in,
                              void* d_out, int out_size, void* d_ws, size_t ws_size,
                              hipStream_t stream) {
  const float* x    = (const float*)d_in[0];
  const float* mu   = (const float*)d_in[1];
  const float* rho  = (const float*)d_in[2];
  const float* beta = (const float*)d_in[3];
  float* out = (float*)d_out;
  float* ws  = (float*)d_ws;

  hipLaunchKernelGGL(k_slice, dim3(NSLICE * NRG), dim3(512), 0, stream,
                     x, mu, rho, ws);
  hipLaunchKernelGGL(k_mid,   dim3(NBLK_MID), dim3(512), 0, stream,
                     beta, ws, out);
  hipLaunchKernelGGL(k_final, dim3(256), dim3(512), 0, stream, ws, out);
}